// Round 1
// baseline (1559.660 us; speedup 1.0000x reference)
//
#include <hip/hip_runtime.h>
#include <math.h>

#define BH 4
#define HH 128
#define WW 128

// ---------------------------------------------------------------------------
// Direct 3x3 conv, SAME pad, NCHW. Block = 256 threads = 16x16 pixel tile,
// 8 output channels per block. Input channel staged via LDS; weights read
// through uniform addresses (scalar loads -> SGPR operand in FMA).
// ---------------------------------------------------------------------------
template<int CIN, bool CONCAT, bool ACT>
__global__ __launch_bounds__(256) void conv3x3_k(
    const float* __restrict__ in0, const float* __restrict__ in1,
    const float* __restrict__ in2, const float* __restrict__ w,
    const float* __restrict__ bias, float* __restrict__ out, int Cout)
{
    __shared__ float tile[18 * 18];
    const int tid = threadIdx.x;
    const int tx = tid & 15, ty = tid >> 4;
    const int ogroups = Cout >> 3;
    const int b  = blockIdx.z / ogroups;
    const int og = blockIdx.z % ogroups;
    const int x0 = blockIdx.x * 16, y0 = blockIdx.y * 16;
    const float* wblk = w + (size_t)og * 8 * CIN * 9;

    float acc[8];
#pragma unroll
    for (int o = 0; o < 8; ++o) acc[o] = 0.f;

    for (int ic = 0; ic < CIN; ++ic) {
        const float* src;
        if (CONCAT) {
            src = (ic < 64)  ? in0 + ((size_t)b * 64 + ic) * HH * WW
                : (ic < 128) ? in1 + ((size_t)b * 64 + (ic - 64)) * HH * WW
                             : in2 + ((size_t)b * 2  + (ic - 128)) * HH * WW;
        } else {
            src = in0 + ((size_t)b * CIN + ic) * HH * WW;
        }
        __syncthreads();
        for (int i = tid; i < 18 * 18; i += 256) {
            int r = i / 18, c = i - r * 18;
            int yy = y0 + r - 1, xx = x0 + c - 1;
            float v = 0.f;
            if (yy >= 0 && yy < HH && xx >= 0 && xx < WW) v = src[yy * WW + xx];
            tile[i] = v;
        }
        __syncthreads();

        float v[9];
#pragma unroll
        for (int ky = 0; ky < 3; ++ky)
#pragma unroll
            for (int kx = 0; kx < 3; ++kx)
                v[ky * 3 + kx] = tile[(ty + ky) * 18 + tx + kx];

        const float* wic = wblk + ic * 9;   // uniform across block -> s_load
#pragma unroll
        for (int o = 0; o < 8; ++o) {
#pragma unroll
            for (int k = 0; k < 9; ++k)
                acc[o] = fmaf(v[k], wic[o * CIN * 9 + k], acc[o]);
        }
    }

    const int yy = y0 + ty, xx = x0 + tx;
#pragma unroll
    for (int o = 0; o < 8; ++o) {
        int oc = og * 8 + o;
        float r = acc[o] + bias[oc];
        if (ACT) r = (r >= 0.f) ? r : 0.1f * r;
        out[(((size_t)b * Cout + oc) * HH + yy) * WW + xx] = r;
    }
}

// ---------------------------------------------------------------------------
// Fused DCNv2: offset transform (10*tanh(o)+flow, sigmoid(mask)) + bilinear
// sampling into LDS, then 64x576 einsum per pixel.
// Block = 256 threads covers 16 consecutive pixels on one row.
// Phase 2: thread = (o4, p) computes 4 output channels for 1 pixel.
// ---------------------------------------------------------------------------
__global__ __launch_bounds__(256) void dcn_k(
    const float* __restrict__ x, const float* __restrict__ flow,
    const float* __restrict__ out4, const float* __restrict__ wt,
    const float* __restrict__ bias, float* __restrict__ out)
{
    __shared__ float s[16 * 580];   // [p][ck], padded to 580 for banks
    const int tid = threadIdx.x;
    const int b = blockIdx.z, y = blockIdx.y, xb = blockIdx.x * 16;
    const size_t hw = (size_t)HH * WW;
    const size_t bo4 = (size_t)b * 432 * hw;

    // ---- phase 1: sample s[p][c*9+k] for 16 pixels, 64 ch, 9 taps ----
    for (int t = tid; t < 16 * 144; t += 256) {
        int p = t & 15, r = t >> 4;          // r = dg*9 + k
        int dg = r / 9, k = r - dg * 9;
        int xp = xb + p;
        size_t pix = (size_t)y * WW + xp;

        float dy = 10.f * tanhf(out4[bo4 + (size_t)(2 * r) * hw + pix])
                 + flow[((size_t)b * 2 + 1) * hw + pix];
        float dx = 10.f * tanhf(out4[bo4 + (size_t)(2 * r + 1) * hw + pix])
                 + flow[((size_t)b * 2 + 0) * hw + pix];
        float m  = 1.f / (1.f + expf(-out4[bo4 + (size_t)(288 + r) * hw + pix]));

        int ki = k / 3, kj = k - ki * 3;
        float py = dy + (float)(y  - 1 + ki);
        float px = dx + (float)(xp - 1 + kj);
        float fy = floorf(py), fx = floorf(px);
        int iy0 = (int)fy, ix0 = (int)fx;
        float wy1 = py - fy, wx1 = px - fx;
        float wy0 = 1.f - wy1, wx0 = 1.f - wx1;
        int iy1 = iy0 + 1, ix1 = ix0 + 1;
        bool vy0 = (iy0 >= 0) & (iy0 < HH), vy1 = (iy1 >= 0) & (iy1 < HH);
        bool vx0 = (ix0 >= 0) & (ix0 < WW), vx1 = (ix1 >= 0) & (ix1 < WW);
        float w00 = (vy0 & vx0) ? wy0 * wx0 : 0.f;
        float w01 = (vy0 & vx1) ? wy0 * wx1 : 0.f;
        float w10 = (vy1 & vx0) ? wy1 * wx0 : 0.f;
        float w11 = (vy1 & vx1) ? wy1 * wx1 : 0.f;
        int cy0 = min(max(iy0, 0), HH - 1), cy1 = min(max(iy1, 0), HH - 1);
        int cx0 = min(max(ix0, 0), WW - 1), cx1 = min(max(ix1, 0), WW - 1);
        int i00 = cy0 * WW + cx0, i01 = cy0 * WW + cx1;
        int i10 = cy1 * WW + cx0, i11 = cy1 * WW + cx1;

        const float* xg = x + ((size_t)b * 64 + dg * 4) * hw;
#pragma unroll
        for (int cg = 0; cg < 4; ++cg) {
            const float* xc = xg + cg * hw;
            float v = w00 * xc[i00] + w01 * xc[i01]
                    + w10 * xc[i10] + w11 * xc[i11];
            s[p * 580 + (dg * 4 + cg) * 9 + k] = v * m;
        }
    }
    __syncthreads();

    // ---- phase 2: out[o] = sum_ck s[ck] * wt[o][ck] + bias ----
    const int o4 = tid >> 4, p = tid & 15;
    const int obase = o4 * 4;
    float acc[4] = {0.f, 0.f, 0.f, 0.f};
    for (int ck = 0; ck < 576; ck += 4) {
        float4 sv = *(const float4*)&s[p * 580 + ck];
#pragma unroll
        for (int j = 0; j < 4; ++j) {
            float4 wv = *(const float4*)&wt[(size_t)(obase + j) * 576 + ck];
            acc[j] = fmaf(sv.x, wv.x, acc[j]);
            acc[j] = fmaf(sv.y, wv.y, acc[j]);
            acc[j] = fmaf(sv.z, wv.z, acc[j]);
            acc[j] = fmaf(sv.w, wv.w, acc[j]);
        }
    }
#pragma unroll
    for (int j = 0; j < 4; ++j) {
        int o = obase + j;
        out[(((size_t)b * 64 + o) * HH + y) * WW + xb + p] = acc[j] + bias[o];
    }
}

// ---------------------------------------------------------------------------
extern "C" void kernel_launch(void* const* d_in, const int* in_sizes, int n_in,
                              void* d_out, int out_size, void* d_ws, size_t ws_size,
                              hipStream_t stream)
{
    const float* x    = (const float*)d_in[0];
    const float* xfw  = (const float*)d_in[1];
    const float* xcur = (const float*)d_in[2];
    const float* flow = (const float*)d_in[3];
    const float* w1   = (const float*)d_in[4];
    const float* b1   = (const float*)d_in[5];
    const float* w2   = (const float*)d_in[6];
    const float* b2   = (const float*)d_in[7];
    const float* w3   = (const float*)d_in[8];
    const float* b3   = (const float*)d_in[9];
    const float* w4   = (const float*)d_in[10];
    const float* b4   = (const float*)d_in[11];
    const float* wt   = (const float*)d_in[12];
    const float* bs   = (const float*)d_in[13];

    const size_t hw = (size_t)HH * WW;
    float* out4 = (float*)d_ws;                       // B*432*H*W
    float* h1   = out4 + (size_t)BH * 432 * hw;       // B*64*H*W
    float* h2   = h1 + (size_t)BH * 64 * hw;          // B*64*H*W
    float* h3   = h1;                                 // reuse h1 region

    dim3 blk(256);
    conv3x3_k<130, true,  true ><<<dim3(8, 8, BH * 8),  blk, 0, stream>>>(xfw, xcur, flow, w1, b1, h1, 64);
    conv3x3_k<64,  false, true ><<<dim3(8, 8, BH * 8),  blk, 0, stream>>>(h1, nullptr, nullptr, w2, b2, h2, 64);
    conv3x3_k<64,  false, true ><<<dim3(8, 8, BH * 8),  blk, 0, stream>>>(h2, nullptr, nullptr, w3, b3, h3, 64);
    conv3x3_k<64,  false, false><<<dim3(8, 8, BH * 54), blk, 0, stream>>>(h3, nullptr, nullptr, w4, b4, out4, 432);
    dcn_k<<<dim3(WW / 16, HH, BH), blk, 0, stream>>>(x, flow, out4, wt, bs, (float*)d_out);
}

// Round 3
// 293.916 us; speedup vs baseline: 5.3065x; 5.3065x over previous
//
#include <hip/hip_runtime.h>
#include <math.h>
#include <type_traits>

#define BH 4
#define HH 128
#define WW 128
#define HW (HH * WW)

typedef __attribute__((ext_vector_type(8))) short bf16x8;
typedef __attribute__((ext_vector_type(4))) float f32x4;

__device__ inline short f2bf(float f) {
    union { float f; unsigned u; } x; x.f = f;
    unsigned r = x.u + 0x7fff + ((x.u >> 16) & 1);   // RNE
    return (short)(r >> 16);
}
__device__ inline float bf2f(short h) {
    union { unsigned u; float f; } x; x.u = ((unsigned)(unsigned short)h) << 16;
    return x.f;
}

// ---------------------------------------------------------------------------
// Repack f32 weights [M][Cin][T] into bf16 MFMA A-fragments.
// Frag f = (kc*T + tap)*MT + mt ; lane l elem i = W[mt*16+(l&15)][kc*32+(l>>4)*8+i][tap]
// (zero-padded past M / Cin). One thread per lane -> one 16B store.
// ---------------------------------------------------------------------------
__global__ void repack_k(const float* __restrict__ w, short* __restrict__ dst,
                         int M, int Cin, int T, int MT, int KC)
{
    int g = blockIdx.x * blockDim.x + threadIdx.x;
    int total = KC * T * MT * 64;
    if (g >= total) return;
    int lane = g & 63;
    int f = g >> 6;
    int mt = f % MT;
    int kt = f / MT;
    int tap = kt % T;
    int kc = kt / T;
    int m = mt * 16 + (lane & 15);
    int ic0 = kc * 32 + (lane >> 4) * 8;
    short v[8];
#pragma unroll
    for (int i = 0; i < 8; ++i) {
        int ic = ic0 + i;
        float x = (m < M && ic < Cin) ? w[((size_t)m * Cin + ic) * T + tap] : 0.f;
        v[i] = f2bf(x);
    }
    *(bf16x8*)(dst + (size_t)g * 8) = *(const bf16x8*)v;
}

template<typename T> __device__ inline float ldval(const T* p, size_t idx) {
    if constexpr (std::is_same<T, float>::value) return p[idx];
    else return bf2f(((const short*)p)[idx]);
}

// ---------------------------------------------------------------------------
// Implicit-GEMM 3x3 conv via mfma_f32_16x16x32_bf16.
// Block: 256 thr = 4 waves. Tile: M=64 (wave w -> rows w*16..), N=64 pixels
// (row y, x0..x0+63). K-loop: 32-channel chunks x 9 taps.
// LDS: X[3 rows][66 cols][40 ic-pad] bf16 -> B-frag = one ds_read_b128.
// ---------------------------------------------------------------------------
template<int CIN, int KC, bool CONCAT, bool ACT, typename Tin>
__global__ __launch_bounds__(256) void conv_mfma_k(
    const Tin* __restrict__ in0, const Tin* __restrict__ in1,
    const float* __restrict__ in2, const short* __restrict__ wp,
    const float* __restrict__ bias, short* __restrict__ out,
    int Cout, int MB, int MT)
{
    __shared__ alignas(16) short X[3 * 66 * 40];
    const int tid = threadIdx.x;
    const int lane = tid & 63, wv = tid >> 6;
    const int x0 = blockIdx.x * 64, y = blockIdx.y;
    const int zb = blockIdx.z;
    const int b = zb / MB, mb = zb % MB;
    const int m0 = mb * 64 + wv * 16;
    const bool mact = (m0 < Cout);
    const int mtg = mb * 4 + wv;

    f32x4 acc[4] = {};

    for (int kc = 0; kc < KC; ++kc) {
        __syncthreads();
        if (tid < 198) {
            int r = tid / 66, c = tid - r * 66;
            int yy = y + r - 1, xx = x0 + c - 1;
            bool inb = (yy >= 0 && yy < HH && xx >= 0 && xx < WW);
            size_t poff = inb ? ((size_t)yy * WW + xx) : 0;
            short* dstp = &X[(r * 66 + c) * 40];
#pragma unroll
            for (int g = 0; g < 4; ++g) {
                short tmp[8];
#pragma unroll
                for (int i = 0; i < 8; ++i) {
                    int ic = kc * 32 + g * 8 + i;
                    float v = 0.f;
                    if (inb && ic < CIN) {
                        if (CONCAT) {
                            v = (ic < 64)  ? ldval(in0, ((size_t)b * 64 + ic) * HW + poff)
                              : (ic < 128) ? ldval(in1, ((size_t)b * 64 + ic - 64) * HW + poff)
                                           : in2[((size_t)b * 2 + ic - 128) * HW + poff];
                        } else {
                            v = ldval(in0, ((size_t)b * CIN + ic) * HW + poff);
                        }
                    }
                    tmp[i] = f2bf(v);
                }
                *(bf16x8*)&dstp[g * 8] = *(const bf16x8*)tmp;
            }
        }
        __syncthreads();
        if (!mact) continue;
#pragma unroll
        for (int tap = 0; tap < 9; ++tap) {
            const int dy = tap / 3, dx = tap - dy * 3;
            bf16x8 a = *(const bf16x8*)(wp + (((size_t)(kc * 9 + tap) * MT + mtg) * 64 + lane) * 8);
#pragma unroll
            for (int nt = 0; nt < 4; ++nt) {
                int c = nt * 16 + (lane & 15) + dx;
                bf16x8 bb = *(const bf16x8*)&X[(dy * 66 + c) * 40 + (lane >> 4) * 8];
                acc[nt] = __builtin_amdgcn_mfma_f32_16x16x32_bf16(a, bb, acc[nt], 0, 0, 0);
            }
        }
    }
    if (!mact) return;

    const int xl = lane & 15, rg = lane >> 4;
#pragma unroll
    for (int nt = 0; nt < 4; ++nt) {
        int xx = x0 + nt * 16 + xl;
#pragma unroll
        for (int j = 0; j < 4; ++j) {
            int o = m0 + rg * 4 + j;
            float r = acc[nt][j] + bias[o];
            if (ACT) r = (r >= 0.f) ? r : 0.1f * r;
            out[((size_t)b * Cout + o) * HW + (size_t)y * WW + xx] = f2bf(r);
        }
    }
}

// ---------------------------------------------------------------------------
// Fused DCNv2. Phase 1: offset transform + bilinear sample -> s (bf16, LDS).
// Phase 2: 64x576 einsum via 18 MFMAs per wave.
// Block = 256 thr, 16 pixels (one row segment).
// ---------------------------------------------------------------------------
__global__ __launch_bounds__(256) void dcn_k(
    const float* __restrict__ x, const float* __restrict__ flow,
    const short* __restrict__ out4, const short* __restrict__ wtp,
    const float* __restrict__ bias, float* __restrict__ out)
{
    __shared__ alignas(16) short s[16 * 584];   // [p][ck] ck-stride 584 (1168B)
    const int tid = threadIdx.x;
    const int b = blockIdx.z, y = blockIdx.y, xb = blockIdx.x * 16;
    const size_t hw = (size_t)HW;
    const size_t bo4 = (size_t)b * 432 * hw;

    for (int t = tid; t < 16 * 144; t += 256) {
        int p = t & 15, r = t >> 4;          // r = dg*9 + k
        int dg = r / 9, k = r - dg * 9;
        int xp = xb + p;
        size_t pix = (size_t)y * WW + xp;

        float dy = 10.f * tanhf(bf2f(out4[bo4 + (size_t)(2 * r) * hw + pix]))
                 + flow[((size_t)b * 2 + 1) * hw + pix];
        float dx = 10.f * tanhf(bf2f(out4[bo4 + (size_t)(2 * r + 1) * hw + pix]))
                 + flow[((size_t)b * 2 + 0) * hw + pix];
        float m  = 1.f / (1.f + expf(-bf2f(out4[bo4 + (size_t)(288 + r) * hw + pix])));

        int ki = k / 3, kj = k - ki * 3;
        float py = dy + (float)(y  - 1 + ki);
        float px = dx + (float)(xp - 1 + kj);
        float fy = floorf(py), fx = floorf(px);
        int iy0 = (int)fy, ix0 = (int)fx;
        float wy1 = py - fy, wx1 = px - fx;
        float wy0 = 1.f - wy1, wx0 = 1.f - wx1;
        int iy1 = iy0 + 1, ix1 = ix0 + 1;
        bool vy0 = (iy0 >= 0) & (iy0 < HH), vy1 = (iy1 >= 0) & (iy1 < HH);
        bool vx0 = (ix0 >= 0) & (ix0 < WW), vx1 = (ix1 >= 0) & (ix1 < WW);
        float w00 = (vy0 & vx0) ? wy0 * wx0 : 0.f;
        float w01 = (vy0 & vx1) ? wy0 * wx1 : 0.f;
        float w10 = (vy1 & vx0) ? wy1 * wx0 : 0.f;
        float w11 = (vy1 & vx1) ? wy1 * wx1 : 0.f;
        int cy0 = min(max(iy0, 0), HH - 1), cy1 = min(max(iy1, 0), HH - 1);
        int cx0 = min(max(ix0, 0), WW - 1), cx1 = min(max(ix1, 0), WW - 1);
        int i00 = cy0 * WW + cx0, i01 = cy0 * WW + cx1;
        int i10 = cy1 * WW + cx0, i11 = cy1 * WW + cx1;

        const float* xg = x + ((size_t)b * 64 + dg * 4) * hw;
#pragma unroll
        for (int cg = 0; cg < 4; ++cg) {
            const float* xc = xg + cg * hw;
            float v = w00 * xc[i00] + w01 * xc[i01]
                    + w10 * xc[i10] + w11 * xc[i11];
            s[p * 584 + (dg * 4 + cg) * 9 + k] = f2bf(v * m);
        }
    }
    __syncthreads();

    const int lane = tid & 63, wv = tid >> 6;
    f32x4 acc = {};
    for (int kc = 0; kc < 18; ++kc) {
        bf16x8 a = *(const bf16x8*)(wtp + (((size_t)kc * 4 + wv) * 64 + lane) * 8);
        bf16x8 bb = *(const bf16x8*)&s[(lane & 15) * 584 + kc * 32 + (lane >> 4) * 8];
        acc = __builtin_amdgcn_mfma_f32_16x16x32_bf16(a, bb, acc, 0, 0, 0);
    }
    const int p = lane & 15, rg = lane >> 4;
#pragma unroll
    for (int j = 0; j < 4; ++j) {
        int o = wv * 16 + rg * 4 + j;
        out[((size_t)(b * 64 + o) * HH + y) * WW + xb + p] = acc[j] + bias[o];
    }
}

// ---------------------------------------------------------------------------
extern "C" void kernel_launch(void* const* d_in, const int* in_sizes, int n_in,
                              void* d_out, int out_size, void* d_ws, size_t ws_size,
                              hipStream_t stream)
{
    const float* x    = (const float*)d_in[0];
    const float* xfw  = (const float*)d_in[1];
    const float* xcur = (const float*)d_in[2];
    const float* flow = (const float*)d_in[3];
    const float* w1   = (const float*)d_in[4];
    const float* b1   = (const float*)d_in[5];
    const float* w2   = (const float*)d_in[6];
    const float* b2   = (const float*)d_in[7];
    const float* w3   = (const float*)d_in[8];
    const float* b3   = (const float*)d_in[9];
    const float* w4   = (const float*)d_in[10];
    const float* b4   = (const float*)d_in[11];
    const float* wt   = (const float*)d_in[12];
    const float* bs   = (const float*)d_in[13];

    const size_t hw = (size_t)HW;
    short* out4 = (short*)d_ws;                          // B*432*HW bf16
    short* h1   = out4 + (size_t)BH * 432 * hw;          // B*64*HW
    short* h2   = h1 + (size_t)BH * 64 * hw;
    short* wp1  = h2 + (size_t)BH * 64 * hw;             // 180 frags * 512
    short* wp2  = wp1 + (size_t)180 * 512;
    short* wp3  = wp2 + (size_t)72 * 512;
    short* wp4  = wp3 + (size_t)72 * 512;
    short* wtp  = wp4 + (size_t)486 * 512;

    auto rp = [&](const float* w, short* dst, int M, int Cin, int T) {
        int KC = (Cin + 31) / 32, MT = (M + 15) / 16;
        int total = KC * T * MT * 64;
        repack_k<<<(total + 255) / 256, 256, 0, stream>>>(w, dst, M, Cin, T, MT, KC);
    };
    rp(w1, wp1, 64, 130, 9);
    rp(w2, wp2, 64, 64, 9);
    rp(w3, wp3, 64, 64, 9);
    rp(w4, wp4, 432, 64, 9);
    rp(wt, wtp, 64, 576, 1);

    dim3 blk(256);
    conv_mfma_k<130, 5, true,  true,  float><<<dim3(2, 128, BH * 1), blk, 0, stream>>>(
        xfw, xcur, flow, wp1, b1, h1, 64, 1, 4);
    conv_mfma_k<64,  2, false, true,  short><<<dim3(2, 128, BH * 1), blk, 0, stream>>>(
        h1, (const short*)nullptr, (const float*)nullptr, wp2, b2, h2, 64, 1, 4);
    conv_mfma_k<64,  2, false, true,  short><<<dim3(2, 128, BH * 1), blk, 0, stream>>>(
        h2, (const short*)nullptr, (const float*)nullptr, wp3, b3, h1, 64, 1, 4);
    conv_mfma_k<64,  2, false, false, short><<<dim3(2, 128, BH * 7), blk, 0, stream>>>(
        h1, (const short*)nullptr, (const float*)nullptr, wp4, b4, out4, 432, 7, 27);

    dcn_k<<<dim3(WW / 16, HH, BH), blk, 0, stream>>>(x, flow, out4, wtp, bs, (float*)d_out);
}

// Round 4
// 263.344 us; speedup vs baseline: 5.9225x; 1.1161x over previous
//
#include <hip/hip_runtime.h>
#include <math.h>
#include <type_traits>

#define BH 4
#define HH 128
#define WW 128
#define HW (HH * WW)
#define DPX 32   // pixels per dcn block

typedef __attribute__((ext_vector_type(8))) short bf16x8;
typedef __attribute__((ext_vector_type(4))) float f32x4;

__device__ inline short f2bf(float f) {
    union { float f; unsigned u; } x; x.f = f;
    unsigned r = x.u + 0x7fff + ((x.u >> 16) & 1);   // RNE
    return (short)(r >> 16);
}
__device__ inline float bf2f(short h) {
    union { unsigned u; float f; } x; x.u = ((unsigned)(unsigned short)h) << 16;
    return x.f;
}
__device__ inline float bflo(unsigned u) {
    union { unsigned u; float f; } x; x.u = u << 16; return x.f;
}
__device__ inline float bfhi(unsigned u) {
    union { unsigned u; float f; } x; x.u = u & 0xffff0000u; return x.f;
}

// ---------------------------------------------------------------------------
// Repack f32 conv weights [M][Cin][9] into bf16 MFMA A-fragments.
// Frag f = (kc*9 + tap)*MT + mt ; lane l elem i = W[mt*16+(l&15)][kc*32+(l>>4)*8+i][tap]
// ---------------------------------------------------------------------------
__global__ void repack_k(const float* __restrict__ w, short* __restrict__ dst,
                         int M, int Cin, int T, int MT, int KC)
{
    int g = blockIdx.x * blockDim.x + threadIdx.x;
    int total = KC * T * MT * 64;
    if (g >= total) return;
    int lane = g & 63;
    int f = g >> 6;
    int mt = f % MT;
    int kt = f / MT;
    int tap = kt % T;
    int kc = kt / T;
    int m = mt * 16 + (lane & 15);
    int ic0 = kc * 32 + (lane >> 4) * 8;
    short v[8];
#pragma unroll
    for (int i = 0; i < 8; ++i) {
        int ic = ic0 + i;
        float x = (m < M && ic < Cin) ? w[((size_t)m * Cin + ic) * T + tap] : 0.f;
        v[i] = f2bf(x);
    }
    *(bf16x8*)(dst + (size_t)g * 8) = *(const bf16x8*)v;
}

// ---------------------------------------------------------------------------
// Repack deform weight wt (64,64,3,3) with permuted K: ck' = dg*36 + k*4 + cg
// (c = dg*4+cg, k = ki*3+kj). Frag f = kc*4 + mt, kc 0..17, mt 0..3.
// ---------------------------------------------------------------------------
__global__ void repack_wt_k(const float* __restrict__ w, short* __restrict__ dst)
{
    int g = blockIdx.x * blockDim.x + threadIdx.x;
    if (g >= 72 * 64) return;
    int lane = g & 63;
    int f = g >> 6;
    int mt = f & 3, kc = f >> 2;
    int m = mt * 16 + (lane & 15);
    int ck0 = kc * 32 + (lane >> 4) * 8;
    short v[8];
#pragma unroll
    for (int i = 0; i < 8; ++i) {
        int ck = ck0 + i;                     // < 576
        int dg = ck / 36, rem = ck % 36;
        int k = rem >> 2, cg = rem & 3;
        int c = dg * 4 + cg;
        v[i] = f2bf(w[((size_t)m * 64 + c) * 9 + k]);
    }
    *(bf16x8*)(dst + (size_t)g * 8) = *(const bf16x8*)v;
}

// ---------------------------------------------------------------------------
// NCHW f32 -> NHWC bf16 transpose of x. One thread = one pixel (all 64 ch).
// Reads coalesced per channel; writes 8x16B per thread.
// ---------------------------------------------------------------------------
__global__ __launch_bounds__(256) void nhwc_k(const float* __restrict__ x,
                                              short* __restrict__ xt)
{
    int tid = threadIdx.x;
    int b = blockIdx.y;
    int px = blockIdx.x * 256 + tid;
    const float* src = x + (size_t)b * 64 * HW + px;
    short v[64];
#pragma unroll
    for (int c = 0; c < 64; ++c) v[c] = f2bf(src[(size_t)c * HW]);
    short* dst = xt + ((size_t)b * HW + px) * 64;
#pragma unroll
    for (int q = 0; q < 8; ++q)
        *(bf16x8*)(dst + q * 8) = *(const bf16x8*)&v[q * 8];
}

template<typename T> __device__ inline float ldval(const T* p, size_t idx) {
    if constexpr (std::is_same<T, float>::value) return p[idx];
    else return bf2f(((const short*)p)[idx]);
}

// ---------------------------------------------------------------------------
// Implicit-GEMM 3x3 conv via mfma_f32_16x16x32_bf16 (unchanged from round 3).
// ---------------------------------------------------------------------------
template<int CIN, int KC, bool CONCAT, bool ACT, typename Tin>
__global__ __launch_bounds__(256) void conv_mfma_k(
    const Tin* __restrict__ in0, const Tin* __restrict__ in1,
    const float* __restrict__ in2, const short* __restrict__ wp,
    const float* __restrict__ bias, short* __restrict__ out,
    int Cout, int MB, int MT)
{
    __shared__ alignas(16) short X[3 * 66 * 40];
    const int tid = threadIdx.x;
    const int lane = tid & 63, wv = tid >> 6;
    const int x0 = blockIdx.x * 64, y = blockIdx.y;
    const int zb = blockIdx.z;
    const int b = zb / MB, mb = zb % MB;
    const int m0 = mb * 64 + wv * 16;
    const bool mact = (m0 < Cout);
    const int mtg = mb * 4 + wv;

    f32x4 acc[4] = {};

    for (int kc = 0; kc < KC; ++kc) {
        __syncthreads();
        if (tid < 198) {
            int r = tid / 66, c = tid - r * 66;
            int yy = y + r - 1, xx = x0 + c - 1;
            bool inb = (yy >= 0 && yy < HH && xx >= 0 && xx < WW);
            size_t poff = inb ? ((size_t)yy * WW + xx) : 0;
            short* dstp = &X[(r * 66 + c) * 40];
#pragma unroll
            for (int g = 0; g < 4; ++g) {
                short tmp[8];
#pragma unroll
                for (int i = 0; i < 8; ++i) {
                    int ic = kc * 32 + g * 8 + i;
                    float v = 0.f;
                    if (inb && ic < CIN) {
                        if (CONCAT) {
                            v = (ic < 64)  ? ldval(in0, ((size_t)b * 64 + ic) * HW + poff)
                              : (ic < 128) ? ldval(in1, ((size_t)b * 64 + ic - 64) * HW + poff)
                                           : in2[((size_t)b * 2 + ic - 128) * HW + poff];
                        } else {
                            v = ldval(in0, ((size_t)b * CIN + ic) * HW + poff);
                        }
                    }
                    tmp[i] = f2bf(v);
                }
                *(bf16x8*)&dstp[g * 8] = *(const bf16x8*)tmp;
            }
        }
        __syncthreads();
        if (!mact) continue;
#pragma unroll
        for (int tap = 0; tap < 9; ++tap) {
            const int dy = tap / 3, dx = tap - dy * 3;
            bf16x8 a = *(const bf16x8*)(wp + (((size_t)(kc * 9 + tap) * MT + mtg) * 64 + lane) * 8);
#pragma unroll
            for (int nt = 0; nt < 4; ++nt) {
                int c = nt * 16 + (lane & 15) + dx;
                bf16x8 bb = *(const bf16x8*)&X[(dy * 66 + c) * 40 + (lane >> 4) * 8];
                acc[nt] = __builtin_amdgcn_mfma_f32_16x16x32_bf16(a, bb, acc[nt], 0, 0, 0);
            }
        }
    }
    if (!mact) return;

    const int xl = lane & 15, rg = lane >> 4;
#pragma unroll
    for (int nt = 0; nt < 4; ++nt) {
        int xx = x0 + nt * 16 + xl;
#pragma unroll
        for (int j = 0; j < 4; ++j) {
            int o = m0 + rg * 4 + j;
            float r = acc[nt][j] + bias[o];
            if (ACT) r = (r >= 0.f) ? r : 0.1f * r;
            out[((size_t)b * Cout + o) * HW + (size_t)y * WW + xx] = f2bf(r);
        }
    }
}

// ---------------------------------------------------------------------------
// Fused DCNv2, NHWC-gather version. Block = 256 thr, DPX=32 pixels of a row.
// Phase 1: fast tanh/sigmoid + 8B NHWC corner gathers -> packed LDS store.
// Phase 2: 64x576 einsum, 2 MFMA tiles per wave.
// s layout: [p][ck'] with ck' = dg*36 + k*4 + cg, p-stride 584 (1168B: 2-way
// bank alias only on b128 reads = free).
// ---------------------------------------------------------------------------
__global__ __launch_bounds__(256) void dcn_k(
    const short* __restrict__ xt, const float* __restrict__ flow,
    const short* __restrict__ out4, const short* __restrict__ wtp,
    const float* __restrict__ bias, float* __restrict__ out)
{
    __shared__ alignas(16) short s[DPX * 584];
    __shared__ float fl[2][DPX];
    const int tid = threadIdx.x;
    const int b = blockIdx.z, y = blockIdx.y, xb = blockIdx.x * DPX;
    const size_t hw = (size_t)HW;
    const short* o4b = out4 + (size_t)b * 432 * hw + (size_t)y * WW + xb;
    constexpr float L2E = 1.4426950408889634f;

    if (tid < 2 * DPX) {
        int j = tid >> 5, p = tid & (DPX - 1);
        fl[j][p] = flow[((size_t)b * 2 + j) * hw + (size_t)y * WW + xb + p];
    }
    __syncthreads();

    const short* xtb = xt + (size_t)b * hw * 64;

#pragma unroll
    for (int it = 0; it < DPX * 144 / 256; ++it) {
        int t = tid + it * 256;
        int p = t & (DPX - 1), r = t >> 5;
        int dg = r / 9, k = r - dg * 9;
        int xp = xb + p;

        float ody = bf2f(o4b[(size_t)(2 * r) * hw + p]);
        float odx = bf2f(o4b[(size_t)(2 * r + 1) * hw + p]);
        float omk = bf2f(o4b[(size_t)(288 + r) * hw + p]);

        float tdy = 1.f - 2.f * __builtin_amdgcn_rcpf(__builtin_amdgcn_exp2f(2.f * L2E * ody) + 1.f);
        float tdx = 1.f - 2.f * __builtin_amdgcn_rcpf(__builtin_amdgcn_exp2f(2.f * L2E * odx) + 1.f);
        float m   = __builtin_amdgcn_rcpf(1.f + __builtin_amdgcn_exp2f(-L2E * omk));

        float dyf = 10.f * tdy + fl[1][p];
        float dxf = 10.f * tdx + fl[0][p];

        int ki = k / 3, kj = k - ki * 3;
        float py = dyf + (float)(y  - 1 + ki);
        float px = dxf + (float)(xp - 1 + kj);
        float fy = floorf(py), fx = floorf(px);
        int iy0 = (int)fy, ix0 = (int)fx;
        float wy1 = py - fy, wx1 = px - fx;
        float wy0 = 1.f - wy1, wx0 = 1.f - wx1;
        int iy1 = iy0 + 1, ix1 = ix0 + 1;
        bool vy0 = (iy0 >= 0) & (iy0 < HH), vy1 = (iy1 >= 0) & (iy1 < HH);
        bool vx0 = (ix0 >= 0) & (ix0 < WW), vx1 = (ix1 >= 0) & (ix1 < WW);
        float w00 = (vy0 & vx0) ? wy0 * wx0 : 0.f;
        float w01 = (vy0 & vx1) ? wy0 * wx1 : 0.f;
        float w10 = (vy1 & vx0) ? wy1 * wx0 : 0.f;
        float w11 = (vy1 & vx1) ? wy1 * wx1 : 0.f;
        int cy0 = min(max(iy0, 0), HH - 1), cy1 = min(max(iy1, 0), HH - 1);
        int cx0 = min(max(ix0, 0), WW - 1), cx1 = min(max(ix1, 0), WW - 1);
        const short* xg = xtb + dg * 4;
        uint2 d00 = *(const uint2*)(xg + (size_t)(cy0 * WW + cx0) * 64);
        uint2 d01 = *(const uint2*)(xg + (size_t)(cy0 * WW + cx1) * 64);
        uint2 d10 = *(const uint2*)(xg + (size_t)(cy1 * WW + cx0) * 64);
        uint2 d11 = *(const uint2*)(xg + (size_t)(cy1 * WW + cx1) * 64);

        float a0 = w00 * bflo(d00.x) + w01 * bflo(d01.x) + w10 * bflo(d10.x) + w11 * bflo(d11.x);
        float a1 = w00 * bfhi(d00.x) + w01 * bfhi(d01.x) + w10 * bfhi(d10.x) + w11 * bfhi(d11.x);
        float a2 = w00 * bflo(d00.y) + w01 * bflo(d01.y) + w10 * bflo(d10.y) + w11 * bflo(d11.y);
        float a3 = w00 * bfhi(d00.y) + w01 * bfhi(d01.y) + w10 * bfhi(d10.y) + w11 * bfhi(d11.y);

        unsigned r0 = ((unsigned)(unsigned short)f2bf(a1 * m) << 16) | (unsigned short)f2bf(a0 * m);
        unsigned r1 = ((unsigned)(unsigned short)f2bf(a3 * m) << 16) | (unsigned short)f2bf(a2 * m);
        uint2 pk; pk.x = r0; pk.y = r1;
        *(uint2*)&s[p * 584 + dg * 36 + k * 4] = pk;
    }
    __syncthreads();

    const int lane = tid & 63, wv = tid >> 6;
    f32x4 acc[DPX / 16] = {};
    for (int kc = 0; kc < 18; ++kc) {
        bf16x8 a = *(const bf16x8*)(wtp + ((size_t)(kc * 4 + wv) * 64 + lane) * 8);
#pragma unroll
        for (int nt = 0; nt < DPX / 16; ++nt) {
            bf16x8 bb = *(const bf16x8*)&s[(nt * 16 + (lane & 15)) * 584 + kc * 32 + (lane >> 4) * 8];
            acc[nt] = __builtin_amdgcn_mfma_f32_16x16x32_bf16(a, bb, acc[nt], 0, 0, 0);
        }
    }
    const int xl = lane & 15, rg = lane >> 4;
#pragma unroll
    for (int nt = 0; nt < DPX / 16; ++nt) {
#pragma unroll
        for (int j = 0; j < 4; ++j) {
            int o = wv * 16 + rg * 4 + j;
            out[((size_t)(b * 64 + o) * HH + y) * WW + xb + nt * 16 + xl] = acc[nt][j] + bias[o];
        }
    }
}

// ---------------------------------------------------------------------------
extern "C" void kernel_launch(void* const* d_in, const int* in_sizes, int n_in,
                              void* d_out, int out_size, void* d_ws, size_t ws_size,
                              hipStream_t stream)
{
    const float* x    = (const float*)d_in[0];
    const float* xfw  = (const float*)d_in[1];
    const float* xcur = (const float*)d_in[2];
    const float* flow = (const float*)d_in[3];
    const float* w1   = (const float*)d_in[4];
    const float* b1   = (const float*)d_in[5];
    const float* w2   = (const float*)d_in[6];
    const float* b2   = (const float*)d_in[7];
    const float* w3   = (const float*)d_in[8];
    const float* b3   = (const float*)d_in[9];
    const float* w4   = (const float*)d_in[10];
    const float* b4   = (const float*)d_in[11];
    const float* wt   = (const float*)d_in[12];
    const float* bs   = (const float*)d_in[13];

    const size_t hw = (size_t)HW;
    short* out4 = (short*)d_ws;                          // B*432*HW bf16
    short* h1   = out4 + (size_t)BH * 432 * hw;          // B*64*HW
    short* h2   = h1 + (size_t)BH * 64 * hw;
    short* wp1  = h2 + (size_t)BH * 64 * hw;
    short* wp2  = wp1 + (size_t)180 * 512;
    short* wp3  = wp2 + (size_t)72 * 512;
    short* wp4  = wp3 + (size_t)72 * 512;
    short* wtp  = wp4 + (size_t)486 * 512;
    short* xt   = wtp + (size_t)72 * 512;                // B*HW*64 bf16 NHWC

    auto rp = [&](const float* w, short* dst, int M, int Cin, int T) {
        int KC = (Cin + 31) / 32, MT = (M + 15) / 16;
        int total = KC * T * MT * 64;
        repack_k<<<(total + 255) / 256, 256, 0, stream>>>(w, dst, M, Cin, T, MT, KC);
    };
    rp(w1, wp1, 64, 130, 9);
    rp(w2, wp2, 64, 64, 9);
    rp(w3, wp3, 64, 64, 9);
    rp(w4, wp4, 432, 64, 9);
    repack_wt_k<<<(72 * 64 + 255) / 256, 256, 0, stream>>>(wt, wtp);
    nhwc_k<<<dim3(HW / 256, BH), 256, 0, stream>>>(x, xt);

    dim3 blk(256);
    conv_mfma_k<130, 5, true,  true,  float><<<dim3(2, 128, BH * 1), blk, 0, stream>>>(
        xfw, xcur, flow, wp1, b1, h1, 64, 1, 4);
    conv_mfma_k<64,  2, false, true,  short><<<dim3(2, 128, BH * 1), blk, 0, stream>>>(
        h1, (const short*)nullptr, (const float*)nullptr, wp2, b2, h2, 64, 1, 4);
    conv_mfma_k<64,  2, false, true,  short><<<dim3(2, 128, BH * 1), blk, 0, stream>>>(
        h2, (const short*)nullptr, (const float*)nullptr, wp3, b3, h1, 64, 1, 4);
    conv_mfma_k<64,  2, false, false, short><<<dim3(2, 128, BH * 7), blk, 0, stream>>>(
        h1, (const short*)nullptr, (const float*)nullptr, wp4, b4, out4, 432, 7, 27);

    dcn_k<<<dim3(WW / DPX, HH, BH), blk, 0, stream>>>(xt, flow, out4, wtp, bs, (float*)d_out);
}